// Round 1
// baseline (1703.852 us; speedup 1.0000x reference)
//
#include <hip/hip_runtime.h>
#include <cstdint>
#include <cstddef>

#define N_NODES 50000
#define N_EDGES 800000
#define HDIM 128
#define TROUNDS 2
#define NT 16   // nodes per update block

static __device__ __forceinline__ float dot4(float4 a, float4 b) {
  return a.x * b.x + a.y * b.y + a.z * b.z + a.w * b.w;
}
static __device__ __forceinline__ float sigmoidf_(float x) {
  return 1.0f / (1.0f + __expf(-x));
}
static __device__ __forceinline__ float tanhf_(float x) {
  float xc = fminf(15.0f, fmaxf(-15.0f, x));
  float a = __expf(2.0f * xc);
  return (a - 1.0f) / (a + 1.0f);
}

// Split W_msg [T,256,257] into aligned Wd [T,256,128], Ws [T,256,128], we [T,256]
__global__ void repack_wmsg(const float* __restrict__ Wmsg, float* __restrict__ Wd,
                            float* __restrict__ Ws, float* __restrict__ we) {
  int i = blockIdx.x * blockDim.x + threadIdx.x;
  const int total = TROUNDS * 256 * 257;
  if (i >= total) return;
  int t = i / (256 * 257);
  int r = i % (256 * 257);
  int j = r / 257, k = r % 257;
  float v = Wmsg[i];
  if (k < 128)      Wd[((size_t)t * 256 + j) * 128 + k] = v;
  else if (k < 256) Ws[((size_t)t * 256 + j) * 128 + (k - 128)] = v;
  else              we[t * 256 + j] = v;
}

__global__ void count_kernel(const int* __restrict__ dst, const float* __restrict__ he,
                             int* __restrict__ deg_i, float* __restrict__ hsum) {
  int e = blockIdx.x * blockDim.x + threadIdx.x;
  if (e >= N_EDGES) return;
  int d = dst[e];
  atomicAdd(&deg_i[d], 1);
  atomicAdd(&hsum[d], he[e]);
}

// single-block exclusive scan over deg_i -> row_start, also init cursor & deg_f
__global__ void scan_kernel(const int* __restrict__ deg_i, int* __restrict__ row_start,
                            int* __restrict__ cursor, float* __restrict__ deg_f,
                            int n, int n_edges) {
  __shared__ int psum[1024];
  int tid = threadIdx.x;
  const int CH = (n + 1023) / 1024;
  int lo = tid * CH, hi = min(lo + CH, n);
  int s = 0;
  for (int i = lo; i < hi; ++i) s += deg_i[i];
  psum[tid] = s;
  __syncthreads();
  for (int off = 1; off < 1024; off <<= 1) {
    int v = psum[tid];
    int add = (tid >= off) ? psum[tid - off] : 0;
    __syncthreads();
    psum[tid] = v + add;
    __syncthreads();
  }
  int base = (tid == 0) ? 0 : psum[tid - 1];
  for (int i = lo; i < hi; ++i) {
    int d = deg_i[i];
    row_start[i] = base;
    cursor[i] = base;
    deg_f[i] = (float)d;
    base += d;
  }
  if (tid == 1023) row_start[n] = psum[1023];
  (void)n_edges;
}

__global__ void fill_kernel(const int* __restrict__ src, const int* __restrict__ dst,
                            int* __restrict__ cursor, int* __restrict__ csr_src) {
  int e = blockIdx.x * blockDim.x + threadIdx.x;
  if (e >= N_EDGES) return;
  int d = dst[e];
  int slot = atomicAdd(&cursor[d], 1);
  csr_src[slot] = src[e];
}

// one wave per node: S[v] = sum over incoming edges of hv[src]
__global__ void gather_kernel(const float* __restrict__ hv, const int* __restrict__ row_start,
                              const int* __restrict__ csr_src, float* __restrict__ S, int n) {
  int wid = (int)((blockIdx.x * blockDim.x + threadIdx.x) >> 6);
  int lane = threadIdx.x & 63;
  if (wid >= n) return;
  int beg = row_start[wid], end = row_start[wid + 1];
  float ax = 0.f, ay = 0.f;
  for (int s = beg; s < end; ++s) {
    int u = csr_src[s];
    const float2 v = *reinterpret_cast<const float2*>(hv + (size_t)u * HDIM + lane * 2);
    ax += v.x; ay += v.y;
  }
  float2 o; o.x = ax; o.y = ay;
  *reinterpret_cast<float2*>(S + (size_t)wid * HDIM + lane * 2) = o;
}

// Fused node update: a = deg*(Wd hv + bmsg) + Ws S + hsum*we ; GRU(a, hv)
__global__ __launch_bounds__(128) void update_kernel(
    const float* __restrict__ hv_in, const float* __restrict__ S,
    const float* __restrict__ deg_f, const float* __restrict__ hsum,
    const float* __restrict__ Wd, const float* __restrict__ Ws, const float* __restrict__ we,
    const float* __restrict__ bmsg,
    const float* __restrict__ Wih, const float* __restrict__ Whh,
    const float* __restrict__ bih, const float* __restrict__ bhh,
    float* __restrict__ hv_out) {
  __shared__ float hv_s[NT][HDIM];
  __shared__ float S_s[NT][HDIM];
  __shared__ float a_s[NT][256];
  __shared__ float deg_sh[NT], hs_sh[NT];

  const int tid = threadIdx.x;         // 0..127
  const int node0 = blockIdx.x * NT;

  {
    const float4* hp = reinterpret_cast<const float4*>(hv_in + (size_t)node0 * HDIM);
    const float4* sp = reinterpret_cast<const float4*>(S + (size_t)node0 * HDIM);
    float4* hd = reinterpret_cast<float4*>(&hv_s[0][0]);
    float4* sd = reinterpret_cast<float4*>(&S_s[0][0]);
    #pragma unroll
    for (int i = 0; i < (NT * HDIM / 4) / 128; ++i) {
      hd[tid + i * 128] = hp[tid + i * 128];
      sd[tid + i * 128] = sp[tid + i * 128];
    }
    if (tid < NT) { deg_sh[tid] = deg_f[node0 + tid]; hs_sh[tid] = hsum[node0 + tid]; }
  }
  __syncthreads();

  // ---- Phase A: a[n][j] for j in {tid, tid+128} ----
  {
    float accd0[NT], accd1[NT], accs0[NT], accs1[NT];
    #pragma unroll
    for (int nn = 0; nn < NT; ++nn) { accd0[nn] = 0.f; accd1[nn] = 0.f; accs0[nn] = 0.f; accs1[nn] = 0.f; }
    const int j0 = tid, j1 = tid + 128;
    const float4* wd0p = reinterpret_cast<const float4*>(Wd + (size_t)j0 * HDIM);
    const float4* wd1p = reinterpret_cast<const float4*>(Wd + (size_t)j1 * HDIM);
    const float4* ws0p = reinterpret_cast<const float4*>(Ws + (size_t)j0 * HDIM);
    const float4* ws1p = reinterpret_cast<const float4*>(Ws + (size_t)j1 * HDIM);
    for (int k4 = 0; k4 < HDIM / 4; ++k4) {
      float4 wd0 = wd0p[k4], wd1 = wd1p[k4], ws0 = ws0p[k4], ws1 = ws1p[k4];
      #pragma unroll
      for (int nn = 0; nn < NT; ++nn) {
        float4 h4 = *reinterpret_cast<const float4*>(&hv_s[nn][k4 * 4]);
        float4 s4 = *reinterpret_cast<const float4*>(&S_s[nn][k4 * 4]);
        accd0[nn] += dot4(wd0, h4);
        accd1[nn] += dot4(wd1, h4);
        accs0[nn] += dot4(ws0, s4);
        accs1[nn] += dot4(ws1, s4);
      }
    }
    const float w0 = we[j0], w1 = we[j1], b0 = bmsg[j0], b1 = bmsg[j1];
    #pragma unroll
    for (int nn = 0; nn < NT; ++nn) {
      float dg = deg_sh[nn], hs = hs_sh[nn];
      a_s[nn][j0] = dg * (accd0[nn] + b0) + accs0[nn] + hs * w0;
      a_s[nn][j1] = dg * (accd1[nn] + b1) + accs1[nn] + hs * w1;
    }
  }
  __syncthreads();

  // ---- Phase B: feature f = tid; gi rows {f, f+128, f+256} over a (K=256); gh over hv (K=128) ----
  {
    const int f = tid;
    float acci0[NT], acci1[NT], acci2[NT];
    #pragma unroll
    for (int nn = 0; nn < NT; ++nn) { acci0[nn] = 0.f; acci1[nn] = 0.f; acci2[nn] = 0.f; }
    {
      const float4* wi0 = reinterpret_cast<const float4*>(Wih + (size_t)f * 256);
      const float4* wi1 = reinterpret_cast<const float4*>(Wih + (size_t)(f + 128) * 256);
      const float4* wi2 = reinterpret_cast<const float4*>(Wih + (size_t)(f + 256) * 256);
      for (int k4 = 0; k4 < 256 / 4; ++k4) {
        float4 a0 = wi0[k4], a1 = wi1[k4], a2 = wi2[k4];
        #pragma unroll
        for (int nn = 0; nn < NT; ++nn) {
          float4 av = *reinterpret_cast<const float4*>(&a_s[nn][k4 * 4]);
          acci0[nn] += dot4(a0, av);
          acci1[nn] += dot4(a1, av);
          acci2[nn] += dot4(a2, av);
        }
      }
    }
    float acch0[NT], acch1[NT], acch2[NT];
    #pragma unroll
    for (int nn = 0; nn < NT; ++nn) { acch0[nn] = 0.f; acch1[nn] = 0.f; acch2[nn] = 0.f; }
    {
      const float4* wh0 = reinterpret_cast<const float4*>(Whh + (size_t)f * HDIM);
      const float4* wh1 = reinterpret_cast<const float4*>(Whh + (size_t)(f + 128) * HDIM);
      const float4* wh2 = reinterpret_cast<const float4*>(Whh + (size_t)(f + 256) * HDIM);
      for (int k4 = 0; k4 < HDIM / 4; ++k4) {
        float4 h0 = wh0[k4], h1 = wh1[k4], h2 = wh2[k4];
        #pragma unroll
        for (int nn = 0; nn < NT; ++nn) {
          float4 hvv = *reinterpret_cast<const float4*>(&hv_s[nn][k4 * 4]);
          acch0[nn] += dot4(h0, hvv);
          acch1[nn] += dot4(h1, hvv);
          acch2[nn] += dot4(h2, hvv);
        }
      }
    }
    const float bi0 = bih[f], bi1 = bih[f + 128], bi2 = bih[f + 256];
    const float bh0 = bhh[f], bh1 = bhh[f + 128], bh2 = bhh[f + 256];
    #pragma unroll
    for (int nn = 0; nn < NT; ++nn) {
      float r = sigmoidf_(acci0[nn] + bi0 + acch0[nn] + bh0);
      float z = sigmoidf_(acci1[nn] + bi1 + acch1[nn] + bh1);
      float ng = tanhf_(acci2[nn] + bi2 + r * (acch2[nn] + bh2));
      float h = hv_s[nn][f];
      hv_out[(size_t)(node0 + nn) * HDIM + f] = (1.f - z) * ng + z * h;
    }
  }
}

extern "C" void kernel_launch(void* const* d_in, const int* in_sizes, int n_in,
                              void* d_out, int out_size, void* d_ws, size_t ws_size,
                              hipStream_t stream) {
  const float* hv   = (const float*)d_in[0];
  const float* he   = (const float*)d_in[1];
  const int*   src  = (const int*)d_in[2];
  const int*   dst  = (const int*)d_in[3];
  const float* Wmsg = (const float*)d_in[4];
  const float* Wih  = (const float*)d_in[6];
  const float* Whh  = (const float*)d_in[7];
  const float* bmsg = (const float*)d_in[5];
  const float* bih  = (const float*)d_in[8];
  const float* bhh  = (const float*)d_in[9];

  char* p = (char*)d_ws;
  auto alloc = [&](size_t bytes) { char* r = p; p += (bytes + 255) & ~(size_t)255; return r; };
  float* S        = (float*)alloc((size_t)N_NODES * HDIM * 4);
  float* deg_f    = (float*)alloc((size_t)N_NODES * 4);
  float* hsum     = (float*)alloc((size_t)N_NODES * 4);
  float* Wd       = (float*)alloc((size_t)TROUNDS * 256 * 128 * 4);
  float* Ws       = (float*)alloc((size_t)TROUNDS * 256 * 128 * 4);
  float* we       = (float*)alloc((size_t)TROUNDS * 256 * 4);
  int*   row_start= (int*)alloc((size_t)(N_NODES + 1) * 4);
  int*   cursor   = (int*)alloc((size_t)N_NODES * 4);
  int*   deg_i    = (int*)alloc((size_t)N_NODES * 4);
  int*   csr_src  = (int*)alloc((size_t)N_EDGES * 4);

  hipMemsetAsync(deg_i, 0, (size_t)N_NODES * 4, stream);
  hipMemsetAsync(hsum, 0, (size_t)N_NODES * 4, stream);

  repack_wmsg<<<(TROUNDS * 256 * 257 + 255) / 256, 256, 0, stream>>>(Wmsg, Wd, Ws, we);
  count_kernel<<<(N_EDGES + 255) / 256, 256, 0, stream>>>(dst, he, deg_i, hsum);
  scan_kernel<<<1, 1024, 0, stream>>>(deg_i, row_start, cursor, deg_f, N_NODES, N_EDGES);
  fill_kernel<<<(N_EDGES + 255) / 256, 256, 0, stream>>>(src, dst, cursor, csr_src);

  const float* hcur = hv;
  float* outp = (float*)d_out;
  for (int t = 0; t < TROUNDS; ++t) {
    gather_kernel<<<(N_NODES + 3) / 4, 256, 0, stream>>>(hcur, row_start, csr_src, S, N_NODES);
    // in-place-safe: each block only touches its own 16 node rows
    update_kernel<<<N_NODES / NT, 128, 0, stream>>>(
        hcur, S, deg_f, hsum,
        Wd + (size_t)t * 256 * 128, Ws + (size_t)t * 256 * 128, we + (size_t)t * 256,
        bmsg + (size_t)t * 256,
        Wih + (size_t)t * 384 * 256, Whh + (size_t)t * 384 * 128,
        bih + (size_t)t * 384, bhh + (size_t)t * 384,
        outp);
    hcur = outp;
  }
  (void)in_sizes; (void)n_in; (void)out_size; (void)ws_size;
}

// Round 2
// 866.424 us; speedup vs baseline: 1.9665x; 1.9665x over previous
//
#include <hip/hip_runtime.h>
#include <cstdint>
#include <cstddef>

#define N_NODES 50000
#define N_EDGES 800000
#define HDIM 128
#define TROUNDS 2
#define NTILES 3125   // N_NODES / 16

typedef __attribute__((ext_vector_type(8))) short short8v;
typedef __attribute__((ext_vector_type(4))) float f32x4;

static __device__ __forceinline__ unsigned short f2bf(float f) {
  uint32_t u = __float_as_uint(f);
  uint32_t r = (u + 0x7FFFu + ((u >> 16) & 1u)) >> 16;
  return (unsigned short)r;
}
static __device__ __forceinline__ float bf2f(unsigned short h) {
  return __uint_as_float(((uint32_t)h) << 16);
}
static __device__ __forceinline__ float sigmoidf_(float x) {
  return 1.0f / (1.0f + __expf(-x));
}
static __device__ __forceinline__ float tanhf_(float x) {
  float xc = fminf(15.0f, fmaxf(-15.0f, x));
  float a = __expf(2.0f * xc);
  return (a - 1.0f) / (a + 1.0f);
}

// ---------------- setup kernels ----------------

__global__ void we_extract(const float* __restrict__ Wmsg, float* __restrict__ we) {
  int i = blockIdx.x * blockDim.x + threadIdx.x;
  if (i >= TROUNDS * 256) return;
  int t = i >> 8, j = i & 255;
  we[i] = Wmsg[((size_t)t * 256 + j) * 257 + 256];
}

// Pack W[J x K] (row stride ldw) into MFMA B-frag layout, bf16 hi/lo.
// frag idx: ((jt*KT + kt)*64 + lane)*8 + e ; j = jt*16 + (lane&15), k = kt*32 + (lane>>4)*8 + e
__global__ void pack_frags(const float* __restrict__ W, unsigned short* __restrict__ Bh,
                           unsigned short* __restrict__ Bl, int JT, int KT, int ldw) {
  int g = blockIdx.x * blockDim.x + threadIdx.x;
  int total = JT * KT * 64;
  if (g >= total) return;
  int lane = g & 63;
  int t = g >> 6;
  int kt = t % KT;
  int jt = t / KT;
  int j = jt * 16 + (lane & 15);
  int k = kt * 32 + (lane >> 4) * 8;
  const float* wp = W + (size_t)j * ldw + k;
  size_t o = (size_t)g * 8;
  #pragma unroll
  for (int e = 0; e < 8; ++e) {
    float f = wp[e];
    unsigned short h = f2bf(f);
    Bh[o + e] = h;
    Bl[o + e] = f2bf(f - bf2f(h));
  }
}

__global__ void count_kernel(const int* __restrict__ dst, const float* __restrict__ he,
                             int* __restrict__ deg_i, float* __restrict__ hsum) {
  int e = blockIdx.x * blockDim.x + threadIdx.x;
  if (e >= N_EDGES) return;
  int d = dst[e];
  atomicAdd(&deg_i[d], 1);
  atomicAdd(&hsum[d], he[e]);
}

__global__ void scan_kernel(const int* __restrict__ deg_i, int* __restrict__ row_start,
                            int* __restrict__ cursor, float* __restrict__ deg_f,
                            int n) {
  __shared__ int psum[1024];
  int tid = threadIdx.x;
  const int CH = (n + 1023) / 1024;
  int lo = tid * CH, hi = min(lo + CH, n);
  int s = 0;
  for (int i = lo; i < hi; ++i) s += deg_i[i];
  psum[tid] = s;
  __syncthreads();
  for (int off = 1; off < 1024; off <<= 1) {
    int v = psum[tid];
    int add = (tid >= off) ? psum[tid - off] : 0;
    __syncthreads();
    psum[tid] = v + add;
    __syncthreads();
  }
  int base = (tid == 0) ? 0 : psum[tid - 1];
  for (int i = lo; i < hi; ++i) {
    int d = deg_i[i];
    row_start[i] = base;
    cursor[i] = base;
    deg_f[i] = (float)d;
    base += d;
  }
  if (tid == 1023) row_start[n] = psum[1023];
}

__global__ void fill_kernel(const int* __restrict__ src, const int* __restrict__ dst,
                            int* __restrict__ cursor, int* __restrict__ csr_src) {
  int e = blockIdx.x * blockDim.x + threadIdx.x;
  if (e >= N_EDGES) return;
  int d = dst[e];
  int slot = atomicAdd(&cursor[d], 1);
  csr_src[slot] = src[e];
}

// one wave per node: S[v] = sum over incoming edges of hv[src]
__global__ void gather_kernel(const float* __restrict__ hv, const int* __restrict__ row_start,
                              const int* __restrict__ csr_src, float* __restrict__ S, int n) {
  int wid = (int)((blockIdx.x * blockDim.x + threadIdx.x) >> 6);
  int lane = threadIdx.x & 63;
  if (wid >= n) return;
  int beg = row_start[wid], end = row_start[wid + 1];
  float ax = 0.f, ay = 0.f;
  for (int s = beg; s < end; ++s) {
    int u = csr_src[s];
    const float2 v = *reinterpret_cast<const float2*>(hv + (size_t)u * HDIM + lane * 2);
    ax += v.x; ay += v.y;
  }
  float2 o; o.x = ax; o.y = ay;
  *reinterpret_cast<float2*>(S + (size_t)wid * HDIM + lane * 2) = o;
}

// ---------------- U1: a = (deg.hv | S) * W1^T + deg*bmsg + hsum*we ----------------
// wave per 16-node tile, MFMA 16x16x32 bf16 hi/lo split, no LDS.
__global__ __launch_bounds__(256) void u1_kernel(
    const float* __restrict__ hv, const float* __restrict__ S,
    const float* __restrict__ deg_f, const float* __restrict__ hsum,
    const unsigned short* __restrict__ B1h, const unsigned short* __restrict__ B1l,
    const float* __restrict__ we, const float* __restrict__ bmsg,
    float* __restrict__ a_out) {
  int tile = blockIdx.x * 4 + (threadIdx.x >> 6);
  if (tile >= NTILES) return;
  int lane = threadIdx.x & 63;
  int rowA = tile * 16 + (lane & 15);
  int koff = (lane >> 4) * 8;

  short8v xh[8], xl[8];
  {
    float deg = deg_f[rowA];
    const float* hrow = hv + (size_t)rowA * HDIM;
    const float* srow = S + (size_t)rowA * HDIM;
    #pragma unroll
    for (int kt = 0; kt < 8; ++kt) {
      const float* src = (kt < 4) ? (hrow + kt * 32 + koff) : (srow + (kt - 4) * 32 + koff);
      float scale = (kt < 4) ? deg : 1.0f;
      #pragma unroll
      for (int e = 0; e < 8; ++e) {
        float f = src[e] * scale;
        unsigned short h = f2bf(f);
        xh[kt][e] = (short)h;
        xl[kt][e] = (short)f2bf(f - bf2f(h));
      }
    }
  }

  f32x4 acc[16];
  #pragma unroll
  for (int jt = 0; jt < 16; ++jt) acc[jt] = (f32x4){0.f, 0.f, 0.f, 0.f};

  #pragma unroll
  for (int kt = 0; kt < 8; ++kt) {
    #pragma unroll
    for (int jt = 0; jt < 16; ++jt) {
      size_t o = ((size_t)(jt * 8 + kt) * 64 + lane) * 8;
      short8v bh = *reinterpret_cast<const short8v*>(B1h + o);
      short8v bl = *reinterpret_cast<const short8v*>(B1l + o);
      acc[jt] = __builtin_amdgcn_mfma_f32_16x16x32_bf16(xh[kt], bh, acc[jt], 0, 0, 0);
      acc[jt] = __builtin_amdgcn_mfma_f32_16x16x32_bf16(xh[kt], bl, acc[jt], 0, 0, 0);
      acc[jt] = __builtin_amdgcn_mfma_f32_16x16x32_bf16(xl[kt], bh, acc[jt], 0, 0, 0);
    }
  }

  // epilogue: C layout col = lane&15 (=j within tile), row = (lane>>4)*4 + reg
  int m0 = (lane >> 4) * 4;
  float degs[4], hss[4];
  #pragma unroll
  for (int rr = 0; rr < 4; ++rr) {
    degs[rr] = deg_f[tile * 16 + m0 + rr];
    hss[rr] = hsum[tile * 16 + m0 + rr];
  }
  #pragma unroll
  for (int jt = 0; jt < 16; ++jt) {
    int j = jt * 16 + (lane & 15);
    float bm = bmsg[j], w = we[j];
    #pragma unroll
    for (int rr = 0; rr < 4; ++rr) {
      a_out[(size_t)(tile * 16 + m0 + rr) * 256 + j] = acc[jt][rr] + degs[rr] * bm + hss[rr] * w;
    }
  }
}

// ---------------- U2: gi = a*Wih^T, gh = hv*Whh^T, GRU gates, write hv ----------------
__global__ __launch_bounds__(256) void u2_kernel(
    const float* __restrict__ hv_in, const float* __restrict__ a_in,
    const unsigned short* __restrict__ B2h, const unsigned short* __restrict__ B2l,
    const unsigned short* __restrict__ B3h, const unsigned short* __restrict__ B3l,
    const float* __restrict__ bih, const float* __restrict__ bhh,
    float* __restrict__ hv_out) {
  int tile = blockIdx.x * 4 + (threadIdx.x >> 6);
  if (tile >= NTILES) return;
  int lane = threadIdx.x & 63;
  int rowA = tile * 16 + (lane & 15);
  int koff = (lane >> 4) * 8;

  short8v ah[8], al[8], hh[4], hl[4];
  {
    const float* ar = a_in + (size_t)rowA * 256 + koff;
    #pragma unroll
    for (int kt = 0; kt < 8; ++kt) {
      #pragma unroll
      for (int e = 0; e < 8; ++e) {
        float f = ar[kt * 32 + e];
        unsigned short h = f2bf(f);
        ah[kt][e] = (short)h;
        al[kt][e] = (short)f2bf(f - bf2f(h));
      }
    }
    const float* hr = hv_in + (size_t)rowA * HDIM + koff;
    #pragma unroll
    for (int kt = 0; kt < 4; ++kt) {
      #pragma unroll
      for (int e = 0; e < 8; ++e) {
        float f = hr[kt * 32 + e];
        unsigned short h = f2bf(f);
        hh[kt][e] = (short)h;
        hl[kt][e] = (short)f2bf(f - bf2f(h));
      }
    }
  }

  int m0 = (lane >> 4) * 4;
  for (int jt = 0; jt < 8; ++jt) {
    f32x4 acc[6];
    #pragma unroll
    for (int q = 0; q < 6; ++q) acc[q] = (f32x4){0.f, 0.f, 0.f, 0.f};

    // gi: K = 256 over a
    #pragma unroll
    for (int kt = 0; kt < 8; ++kt) {
      #pragma unroll
      for (int p = 0; p < 3; ++p) {
        size_t o = ((size_t)((jt + p * 8) * 8 + kt) * 64 + lane) * 8;
        short8v bh = *reinterpret_cast<const short8v*>(B2h + o);
        short8v bl = *reinterpret_cast<const short8v*>(B2l + o);
        acc[p] = __builtin_amdgcn_mfma_f32_16x16x32_bf16(ah[kt], bh, acc[p], 0, 0, 0);
        acc[p] = __builtin_amdgcn_mfma_f32_16x16x32_bf16(ah[kt], bl, acc[p], 0, 0, 0);
        acc[p] = __builtin_amdgcn_mfma_f32_16x16x32_bf16(al[kt], bh, acc[p], 0, 0, 0);
      }
    }
    // gh: K = 128 over hv
    #pragma unroll
    for (int kt = 0; kt < 4; ++kt) {
      #pragma unroll
      for (int p = 0; p < 3; ++p) {
        size_t o = ((size_t)((jt + p * 8) * 4 + kt) * 64 + lane) * 8;
        short8v bh = *reinterpret_cast<const short8v*>(B3h + o);
        short8v bl = *reinterpret_cast<const short8v*>(B3l + o);
        acc[3 + p] = __builtin_amdgcn_mfma_f32_16x16x32_bf16(hh[kt], bh, acc[3 + p], 0, 0, 0);
        acc[3 + p] = __builtin_amdgcn_mfma_f32_16x16x32_bf16(hh[kt], bl, acc[3 + p], 0, 0, 0);
        acc[3 + p] = __builtin_amdgcn_mfma_f32_16x16x32_bf16(hl[kt], bh, acc[3 + p], 0, 0, 0);
      }
    }

    int f = jt * 16 + (lane & 15);
    float bi0 = bih[f], bi1 = bih[f + 128], bi2 = bih[f + 256];
    float bh0 = bhh[f], bh1 = bhh[f + 128], bh2 = bhh[f + 256];
    #pragma unroll
    for (int rr = 0; rr < 4; ++rr) {
      int node = tile * 16 + m0 + rr;
      float r = sigmoidf_(acc[0][rr] + bi0 + acc[3][rr] + bh0);
      float z = sigmoidf_(acc[1][rr] + bi1 + acc[4][rr] + bh1);
      float n = tanhf_(acc[2][rr] + bi2 + r * (acc[5][rr] + bh2));
      float h = hv_in[(size_t)node * HDIM + f];
      hv_out[(size_t)node * HDIM + f] = (1.f - z) * n + z * h;
    }
  }
}

extern "C" void kernel_launch(void* const* d_in, const int* in_sizes, int n_in,
                              void* d_out, int out_size, void* d_ws, size_t ws_size,
                              hipStream_t stream) {
  const float* hv   = (const float*)d_in[0];
  const float* he   = (const float*)d_in[1];
  const int*   src  = (const int*)d_in[2];
  const int*   dst  = (const int*)d_in[3];
  const float* Wmsg = (const float*)d_in[4];
  const float* bmsg = (const float*)d_in[5];
  const float* Wih  = (const float*)d_in[6];
  const float* Whh  = (const float*)d_in[7];
  const float* bih  = (const float*)d_in[8];
  const float* bhh  = (const float*)d_in[9];

  char* p = (char*)d_ws;
  auto alloc = [&](size_t bytes) { char* r = p; p += (bytes + 255) & ~(size_t)255; return r; };
  float* S        = (float*)alloc((size_t)N_NODES * HDIM * 4);
  float* a_buf    = (float*)alloc((size_t)N_NODES * 256 * 4);
  float* deg_f    = (float*)alloc((size_t)N_NODES * 4);
  float* hsum     = (float*)alloc((size_t)N_NODES * 4);
  float* we       = (float*)alloc((size_t)TROUNDS * 256 * 4);
  // packed weight frags (bf16 hi/lo as ushort)
  const size_t B1E = (size_t)16 * 8 * 64 * 8;   // per-round elems = 65536
  const size_t B2E = (size_t)24 * 8 * 64 * 8;   // 98304
  const size_t B3E = (size_t)24 * 4 * 64 * 8;   // 49152
  unsigned short* B1h = (unsigned short*)alloc(TROUNDS * B1E * 2);
  unsigned short* B1l = (unsigned short*)alloc(TROUNDS * B1E * 2);
  unsigned short* B2h = (unsigned short*)alloc(TROUNDS * B2E * 2);
  unsigned short* B2l = (unsigned short*)alloc(TROUNDS * B2E * 2);
  unsigned short* B3h = (unsigned short*)alloc(TROUNDS * B3E * 2);
  unsigned short* B3l = (unsigned short*)alloc(TROUNDS * B3E * 2);
  int* row_start = (int*)alloc((size_t)(N_NODES + 1) * 4);
  int* cursor    = (int*)alloc((size_t)N_NODES * 4);
  int* deg_i     = (int*)alloc((size_t)N_NODES * 4);
  int* csr_src   = (int*)alloc((size_t)N_EDGES * 4);

  hipMemsetAsync(deg_i, 0, (size_t)N_NODES * 4, stream);
  hipMemsetAsync(hsum, 0, (size_t)N_NODES * 4, stream);

  we_extract<<<2, 256, 0, stream>>>(Wmsg, we);
  for (int t = 0; t < TROUNDS; ++t) {
    pack_frags<<<(16 * 8 * 64 + 255) / 256, 256, 0, stream>>>(
        Wmsg + (size_t)t * 256 * 257, B1h + t * B1E, B1l + t * B1E, 16, 8, 257);
    pack_frags<<<(24 * 8 * 64 + 255) / 256, 256, 0, stream>>>(
        Wih + (size_t)t * 384 * 256, B2h + t * B2E, B2l + t * B2E, 24, 8, 256);
    pack_frags<<<(24 * 4 * 64 + 255) / 256, 256, 0, stream>>>(
        Whh + (size_t)t * 384 * 128, B3h + t * B3E, B3l + t * B3E, 24, 4, 128);
  }
  count_kernel<<<(N_EDGES + 255) / 256, 256, 0, stream>>>(dst, he, deg_i, hsum);
  scan_kernel<<<1, 1024, 0, stream>>>(deg_i, row_start, cursor, deg_f, N_NODES);
  fill_kernel<<<(N_EDGES + 255) / 256, 256, 0, stream>>>(src, dst, cursor, csr_src);

  const float* hcur = hv;
  float* outp = (float*)d_out;
  for (int t = 0; t < TROUNDS; ++t) {
    gather_kernel<<<(N_NODES + 3) / 4, 256, 0, stream>>>(hcur, row_start, csr_src, S, N_NODES);
    u1_kernel<<<(NTILES + 3) / 4, 256, 0, stream>>>(
        hcur, S, deg_f, hsum, B1h + t * B1E, B1l + t * B1E,
        we + (size_t)t * 256, bmsg + (size_t)t * 256, a_buf);
    u2_kernel<<<(NTILES + 3) / 4, 256, 0, stream>>>(
        hcur, a_buf, B2h + t * B2E, B2l + t * B2E, B3h + t * B3E, B3l + t * B3E,
        bih + (size_t)t * 384, bhh + (size_t)t * 384, outp);
    hcur = outp;
  }
  (void)in_sizes; (void)n_in; (void)out_size; (void)ws_size; (void)he;
}